// Round 1
// baseline (2563.249 us; speedup 1.0000x reference)
//
#include <hip/hip_runtime.h>
#include <cstdint>
#include <cstddef>

// ---------------------------------------------------------------------------
// PointConv Set Abstraction forward, MI355X (gfx950).
// B=8, N=4096, D=61, S=1024, K=32; MLP 64->64->64->128 ; WeightNet 3->8->8->16
// Output: concat( new_xyz [B,3,S], out [B,128,S] ) fp32.
// ---------------------------------------------------------------------------

constexpr int B_ = 8, N_ = 4096, D_ = 61, S_ = 1024, K_ = 32;
constexpr int P_ = B_ * S_ * K_;          // 262144 positions (b,s,k)
constexpr int BS_ = B_ * S_;              // 8192

// ---------------- workspace layout (bytes) ----------------
constexpr size_t OFF_STATS  = 0;          // zeroed each launch (8192 B)
//   ST0 @ +0    (64*2 dbl), ST1 @ +1024, ST2 @ +2048 (128*2 dbl),
//   SW0 @ +4096 (8*2), SW1 @ +4224, SW2 @ +4352 (16*2), STF @ +4608 (128*2)
constexpr size_t OFF_FPSIDX = 8192;       // 8192 ints
constexpr size_t OFF_NEWXYZ = 40960;      // [B*S][3] f32
constexpr size_t OFF_KNN    = 139264;     // [P] int
constexpr size_t OFF_PT     = 1187840;    // points transposed [B][N][61] f32
constexpr size_t OFF_Y01    = 9183232;    // [64][P] f32 (y0 then y1 in place; later aliased as aggbuf [8192][2048])
constexpr size_t OFF_Y2     = 76292096;   // [128][P] f32
constexpr size_t OFF_W01    = 210509824;  // [8][P] f32 (w0 then w1 in place)
constexpr size_t OFF_W2B    = 218898432;  // [16][P] f32
constexpr size_t OFF_OUTPRE = 235675648;  // [8192][128] f32
// total ~229 MB

// ---------------- host threefry (JAX PRNG reproduction) ----------------
// jax.random.key(42) -> (0,42). Modern JAX default threefry_partitionable=True:
//   split child i = threefry2x32(key, (hi(i), lo(i)))  [full output pair]
//   random_bits 32-bit elem i = bits1 ^ bits2 of threefry2x32(key,(0,i))
// randint span=4096 (pow2) => multiplier==0 => start = lower_bits % 4096 using
// the SECOND split child only.
// FALLBACK MODES if validation fails (flip here next round):
//   MODE 1 (current): bits = b1 ^ b2
//   MODE 2: bits = b1
//   MODE 3: legacy non-partitionable split+bits (iota halves scheme)
static inline uint32_t rotl32(uint32_t x, int r){ return (x << r) | (x >> (32 - r)); }
static void tf2x32(uint32_t k0, uint32_t k1, uint32_t x0, uint32_t x1,
                   uint32_t* o0, uint32_t* o1){
  uint32_t ks[3] = {k0, k1, k0 ^ k1 ^ 0x1BD11BDAu};
  x0 += ks[0]; x1 += ks[1];
  const int RA[4] = {13,15,26,6}, RB[4] = {17,29,16,24};
  for (int i = 0; i < 5; ++i){
    const int* R = (i & 1) ? RB : RA;
    for (int j = 0; j < 4; ++j){ x0 += x1; x1 = rotl32(x1, R[j]); x1 ^= x0; }
    x0 += ks[(i+1)%3]; x1 += ks[(i+2)%3] + (uint32_t)(i+1);
  }
  *o0 = x0; *o1 = x1;
}
struct StartIdx { int v[8]; };
static StartIdx compute_starts(){
  uint32_t ka, kb;
  tf2x32(0u, 42u, 0u, 1u, &ka, &kb);          // split(key)[1]
  StartIdx s;
  for (int i = 0; i < 8; ++i){
    uint32_t b1, b2;
    tf2x32(ka, kb, 0u, (uint32_t)i, &b1, &b2);
    s.v[i] = (int)((b1 ^ b2) & 4095u);        // MODE 1
  }
  return s;
}

// ---------------- transpose points [B,61,N] -> [B,N,61] ----------------
__global__ __launch_bounds__(64) void tr_kernel(const float* __restrict__ pts,
                                                float* __restrict__ pT){
  __shared__ float tile[61][65];
  const int b = blockIdx.x >> 6;
  const int n0 = (blockIdx.x & 63) * 64;
  const int t = threadIdx.x;
  for (int d = 0; d < 61; ++d)
    tile[d][t] = pts[((size_t)b*61 + d)*N_ + n0 + t];
  __syncthreads();
  float* dst = pT + ((size_t)b*N_ + n0 + t)*61;
  for (int d = 0; d < 61; ++d) dst[d] = tile[d][t];
}

// ---------------- FPS: exact reproduction of reference scan ----------------
__global__ __launch_bounds__(256) void fps_kernel(const float* __restrict__ xyz,
                                                  StartIdx st,
                                                  int* __restrict__ fps_idx,
                                                  float* __restrict__ new_xyz,
                                                  float* __restrict__ out_xyz){
  const int b = blockIdx.x, tid = threadIdx.x;
  const int lane = tid & 63, wv = tid >> 6;
  const float* xb = xyz + (size_t)b*3*N_;
  float px[16], py[16], pz[16], dmin[16];
#pragma unroll
  for (int i = 0; i < 16; ++i){
    int n = tid + 256*i;
    px[i] = xb[n]; py[i] = xb[N_ + n]; pz[i] = xb[2*N_ + n];
    dmin[i] = 1e10f;
  }
  __shared__ float s_v[4], s_x[4], s_y[4], s_z[4];
  __shared__ int   s_i[4];
  __shared__ int   s_far;
  __shared__ float s_cx, s_cy, s_cz;

  int far = st.v[b];
  { // broadcast initial centroid from the owning thread (register-held coords)
    int ot = far & 255, oi = far >> 8;
    if (tid == ot){
      float fx = 0.f, fy = 0.f, fz = 0.f;
#pragma unroll
      for (int i = 0; i < 16; ++i){ if (i == oi){ fx = px[i]; fy = py[i]; fz = pz[i]; } }
      s_cx = fx; s_cy = fy; s_cz = fz;
    }
    __syncthreads();
  }
  float cx = s_cx, cy = s_cy, cz = s_cz;

  for (int s = 0; s < S_; ++s){
    if (tid == 0){
      fps_idx[b*S_ + s] = far;
      new_xyz[((size_t)b*S_ + s)*3 + 0] = cx;
      new_xyz[((size_t)b*S_ + s)*3 + 1] = cy;
      new_xyz[((size_t)b*S_ + s)*3 + 2] = cz;
      out_xyz[(size_t)b*3*S_ + s]        = cx;
      out_xyz[(size_t)b*3*S_ + S_ + s]   = cy;
      out_xyz[(size_t)b*3*S_ + 2*S_ + s] = cz;
    }
    float bv = -1.f, bx = 0.f, by = 0.f, bz = 0.f; int bi = 0;
#pragma unroll
    for (int i = 0; i < 16; ++i){
      float dx = __fsub_rn(px[i], cx), dy = __fsub_rn(py[i], cy), dz = __fsub_rn(pz[i], cz);
      float d  = __fadd_rn(__fadd_rn(__fmul_rn(dx,dx), __fmul_rn(dy,dy)), __fmul_rn(dz,dz));
      float dm = fminf(dmin[i], d); dmin[i] = dm;
      if (dm > bv){ bv = dm; bi = tid + 256*i; bx = px[i]; by = py[i]; bz = pz[i]; }
    }
#pragma unroll
    for (int off = 32; off >= 1; off >>= 1){
      float ov = __shfl_xor(bv, off), ox = __shfl_xor(bx, off),
            oy = __shfl_xor(by, off), oz = __shfl_xor(bz, off);
      int   oi = __shfl_xor(bi, off);
      bool take = (ov > bv) || (ov == bv && oi < bi);  // argmax, first index on tie
      if (take){ bv = ov; bi = oi; bx = ox; by = oy; bz = oz; }
    }
    if (lane == 0){ s_v[wv] = bv; s_i[wv] = bi; s_x[wv] = bx; s_y[wv] = by; s_z[wv] = bz; }
    __syncthreads();
    if (tid == 0){
      float v = s_v[0], xx = s_x[0], yy = s_y[0], zz = s_z[0]; int ii = s_i[0];
      for (int w = 1; w < 4; ++w){
        bool take = (s_v[w] > v) || (s_v[w] == v && s_i[w] < ii);
        if (take){ v = s_v[w]; ii = s_i[w]; xx = s_x[w]; yy = s_y[w]; zz = s_z[w]; }
      }
      s_far = ii; s_cx = xx; s_cy = yy; s_cz = zz;
    }
    __syncthreads();
    far = s_far; cx = s_cx; cy = s_cy; cz = s_cz;
  }
}

// ---------------- KNN: 32 smallest sqdist per query, wave per query --------
__global__ __launch_bounds__(256) void knn_kernel(const float* __restrict__ xyz,
                                                  const float* __restrict__ nxyz,
                                                  int* __restrict__ knn_idx){
  __shared__ float dist[4][4096];           // 64 KiB
  const int wv = threadIdx.x >> 6, lane = threadIdx.x & 63;
  const int q = blockIdx.x*4 + wv;          // 0..8191
  const int b = q >> 10;
  const float* xb = xyz + (size_t)b*3*N_;
  const float ax = nxyz[(size_t)q*3], ay = nxyz[(size_t)q*3+1], az = nxyz[(size_t)q*3+2];
  const float sa = __fadd_rn(__fadd_rn(__fmul_rn(ax,ax), __fmul_rn(ay,ay)), __fmul_rn(az,az));
  float* dw = dist[wv];
  float lv = 3.4e38f; int ln = 0;
  for (int i = 0; i < 64; ++i){
    int n = i*64 + lane;
    float x = xb[n], y = xb[N_+n], z = xb[2*N_+n];
    float sb  = __fadd_rn(__fadd_rn(__fmul_rn(x,x), __fmul_rn(y,y)), __fmul_rn(z,z));
    float dot = __fadd_rn(__fadd_rn(__fmul_rn(ax,x), __fmul_rn(ay,y)), __fmul_rn(az,z));
    float d   = __fsub_rn(__fadd_rn(sa, sb), __fmul_rn(2.f, dot));
    dw[n] = d;
    if (d < lv){ lv = d; ln = n; }          // strict <: first index on tie
  }
  __syncthreads();
  int myout = 0;
  for (int r = 0; r < 32; ++r){
    float gv = lv; int gn = ln;
#pragma unroll
    for (int off = 32; off >= 1; off >>= 1){
      float ov = __shfl_xor(gv, off); int on = __shfl_xor(gn, off);
      if (ov < gv || (ov == gv && on < gn)){ gv = ov; gn = on; }
    }
    if (lane == r) myout = gn;
    const int col = gn & 63, row = gn >> 6;
    // cooperative rescan of extracted owner's 64 entries (column col)
    float v = dw[lane*64 + col];
    if (lane == row){ v = 3.4e38f; dw[lane*64 + col] = 3.4e38f; }
    float nv = v; int nn = lane*64 + col;
#pragma unroll
    for (int off = 32; off >= 1; off >>= 1){
      float ov = __shfl_xor(nv, off); int on = __shfl_xor(nn, off);
      if (ov < nv || (ov == nv && on < nn)){ nv = ov; nn = on; }
    }
    if (lane == col){ lv = nv; ln = nn; }   // owner updates its cached local min
  }
  if (lane < 32) knn_idx[(size_t)q*32 + lane] = myout;
}

// ---------------- MLP layer 0: gather + 64->64 + bias -> y [64][P] ---------
__global__ __launch_bounds__(256) void m0_kernel(const float* __restrict__ pT,
                                                 const float* __restrict__ xyz,
                                                 const float* __restrict__ nxyz,
                                                 const int* __restrict__ knn_idx,
                                                 const float* __restrict__ w,
                                                 const float* __restrict__ bias,
                                                 float* __restrict__ y){
  __shared__ float Wt[4096]; __shared__ float bb[64];
  for (int t = threadIdx.x; t < 4096; t += 256){ int o = t >> 6, c = t & 63; Wt[c*64+o] = w[o*64+c]; }
  if (threadIdx.x < 64) bb[threadIdx.x] = bias[threadIdx.x];
  __syncthreads();
  const int p = blockIdx.x*256 + threadIdx.x;
  const int b = p >> 15, s = (p & 32767) >> 5;
  const int n = knn_idx[p];
  float in[64];
  {
    const float* xb = xyz + (size_t)b*3*N_;
    const int q = (b << 10) + s;
    in[0] = xb[n]       - nxyz[(size_t)q*3];
    in[1] = xb[N_+n]    - nxyz[(size_t)q*3+1];
    in[2] = xb[2*N_+n]  - nxyz[(size_t)q*3+2];
    const float* pr = pT + ((size_t)b*N_ + n)*61;
#pragma unroll
    for (int d = 0; d < 61; ++d) in[3+d] = pr[d];
  }
  float acc[64];
#pragma unroll
  for (int o = 0; o < 64; ++o) acc[o] = bb[o];
#pragma unroll
  for (int c = 0; c < 64; ++c){
    float x = in[c];
#pragma unroll
    for (int o = 0; o < 64; o += 4){
      float4 w4 = *reinterpret_cast<const float4*>(&Wt[c*64+o]);
      acc[o]   += x*w4.x; acc[o+1] += x*w4.y; acc[o+2] += x*w4.z; acc[o+3] += x*w4.w;
    }
  }
#pragma unroll
  for (int o = 0; o < 64; ++o) y[(size_t)o*P_ + p] = acc[o];
}

// ---------------- generic channel stats: sum & sumsq (double atomics) ------
__global__ __launch_bounds__(256) void stats_kernel(const float* __restrict__ y,
                                                    double* __restrict__ st, int C){
  const int c = blockIdx.x % C, chunk = blockIdx.x / C;   // 8 chunks of 32768
  const float* row = y + (size_t)c*P_ + (size_t)chunk*32768;
  double s = 0.0, q = 0.0;
  for (int i = threadIdx.x; i < 32768; i += 256){ double v = row[i]; s += v; q += v*v; }
  __shared__ double ss[256], qq[256];
  ss[threadIdx.x] = s; qq[threadIdx.x] = q; __syncthreads();
  for (int w = 128; w >= 1; w >>= 1){
    if (threadIdx.x < w){ ss[threadIdx.x] += ss[threadIdx.x+w]; qq[threadIdx.x] += qq[threadIdx.x+w]; }
    __syncthreads();
  }
  if (threadIdx.x == 0){ atomicAdd(&st[c*2], ss[0]); atomicAdd(&st[c*2+1], qq[0]); }
}

// helper: BN scale/shift from stats (count = P_)
__device__ __forceinline__ void bn_coeff(const double* st, const float* g, const float* be,
                                         int c, double cnt, float* sc, float* sh){
  double mean = st[c*2] / cnt;
  double var  = st[c*2+1] / cnt - mean*mean;
  double scale = (double)g[c] / sqrt(var + 1e-5);
  *sc = (float)scale; *sh = (float)((double)be[c] - mean*scale);
}

// ---------------- MLP layer 1: bn(relu) then 64->64, in place --------------
__global__ __launch_bounds__(256) void m1_kernel(float* __restrict__ y,
                                                 const float* __restrict__ w,
                                                 const float* __restrict__ bias,
                                                 const double* __restrict__ st,
                                                 const float* __restrict__ g,
                                                 const float* __restrict__ be){
  __shared__ float Wt[4096]; __shared__ float bb[64], sc[64], sh[64];
  for (int t = threadIdx.x; t < 4096; t += 256){ int o = t >> 6, c = t & 63; Wt[c*64+o] = w[o*64+c]; }
  if (threadIdx.x < 64){
    bn_coeff(st, g, be, threadIdx.x, (double)P_, &sc[threadIdx.x], &sh[threadIdx.x]);
    bb[threadIdx.x] = bias[threadIdx.x];
  }
  __syncthreads();
  const int p = blockIdx.x*256 + threadIdx.x;
  float in[64];
#pragma unroll
  for (int c = 0; c < 64; ++c){
    float x = y[(size_t)c*P_ + p];
    in[c] = fmaxf(0.f, fmaf(x, sc[c], sh[c]));
  }
  float acc[64];
#pragma unroll
  for (int o = 0; o < 64; ++o) acc[o] = bb[o];
#pragma unroll
  for (int c = 0; c < 64; ++c){
    float x = in[c];
#pragma unroll
    for (int o = 0; o < 64; o += 4){
      float4 w4 = *reinterpret_cast<const float4*>(&Wt[c*64+o]);
      acc[o]   += x*w4.x; acc[o+1] += x*w4.y; acc[o+2] += x*w4.z; acc[o+3] += x*w4.w;
    }
  }
#pragma unroll
  for (int o = 0; o < 64; ++o) y[(size_t)o*P_ + p] = acc[o];
}

// ---------------- MLP layer 2: bn(relu) then 64->128 (half per blockIdx.y) -
__global__ __launch_bounds__(256) void m2_kernel(const float* __restrict__ y1,
                                                 float* __restrict__ y2,
                                                 const float* __restrict__ w,
                                                 const float* __restrict__ bias,
                                                 const double* __restrict__ st,
                                                 const float* __restrict__ g,
                                                 const float* __restrict__ be){
  __shared__ float Wt[4096]; __shared__ float bb[64], sc[64], sh[64];
  const int half = blockIdx.y;
  for (int t = threadIdx.x; t < 4096; t += 256){
    int o = t >> 6, c = t & 63;
    Wt[c*64+o] = w[(size_t)(half*64+o)*64 + c];
  }
  if (threadIdx.x < 64){
    bn_coeff(st, g, be, threadIdx.x, (double)P_, &sc[threadIdx.x], &sh[threadIdx.x]);
    bb[threadIdx.x] = bias[half*64 + threadIdx.x];
  }
  __syncthreads();
  const int p = blockIdx.x*256 + threadIdx.x;
  float in[64];
#pragma unroll
  for (int c = 0; c < 64; ++c){
    float x = y1[(size_t)c*P_ + p];
    in[c] = fmaxf(0.f, fmaf(x, sc[c], sh[c]));
  }
  float acc[64];
#pragma unroll
  for (int o = 0; o < 64; ++o) acc[o] = bb[o];
#pragma unroll
  for (int c = 0; c < 64; ++c){
    float x = in[c];
#pragma unroll
    for (int o = 0; o < 64; o += 4){
      float4 w4 = *reinterpret_cast<const float4*>(&Wt[c*64+o]);
      acc[o]   += x*w4.x; acc[o+1] += x*w4.y; acc[o+2] += x*w4.z; acc[o+3] += x*w4.w;
    }
  }
#pragma unroll
  for (int o = 0; o < 64; ++o) y2[(size_t)(half*64+o)*P_ + p] = acc[o];
}

// ---------------- WeightNet layer 0: gather g_norm, 3->8 ------------------
__global__ __launch_bounds__(256) void w0_kernel(const float* __restrict__ xyz,
                                                 const float* __restrict__ nxyz,
                                                 const int* __restrict__ knn_idx,
                                                 const float* __restrict__ w,   // [8][3]
                                                 const float* __restrict__ bias,
                                                 float* __restrict__ wb){
  __shared__ float Wl[24], bb[8];
  if (threadIdx.x < 24) Wl[threadIdx.x] = w[threadIdx.x];
  if (threadIdx.x < 8)  bb[threadIdx.x] = bias[threadIdx.x];
  __syncthreads();
  const int p = blockIdx.x*256 + threadIdx.x;
  const int b = p >> 15, s = (p & 32767) >> 5;
  const int n = knn_idx[p];
  const float* xb = xyz + (size_t)b*3*N_;
  const int q = (b << 10) + s;
  float gx = xb[n]      - nxyz[(size_t)q*3];
  float gy = xb[N_+n]   - nxyz[(size_t)q*3+1];
  float gz = xb[2*N_+n] - nxyz[(size_t)q*3+2];
#pragma unroll
  for (int o = 0; o < 8; ++o){
    float a = bb[o] + gx*Wl[o*3] + gy*Wl[o*3+1] + gz*Wl[o*3+2];
    wb[(size_t)o*P_ + p] = a;
  }
}

// ---------------- WeightNet layer 1: bn relu 8->8 in place ----------------
__global__ __launch_bounds__(256) void w1_kernel(float* __restrict__ wb,
                                                 const float* __restrict__ w,   // [8][8]
                                                 const float* __restrict__ bias,
                                                 const double* __restrict__ st,
                                                 const float* __restrict__ g,
                                                 const float* __restrict__ be){
  __shared__ float Wl[64], bb[8], sc[8], sh[8];
  if (threadIdx.x < 64) Wl[threadIdx.x] = w[threadIdx.x];
  if (threadIdx.x < 8){
    bn_coeff(st, g, be, threadIdx.x, (double)P_, &sc[threadIdx.x], &sh[threadIdx.x]);
    bb[threadIdx.x] = bias[threadIdx.x];
  }
  __syncthreads();
  const int p = blockIdx.x*256 + threadIdx.x;
  float in[8];
#pragma unroll
  for (int c = 0; c < 8; ++c){
    float x = wb[(size_t)c*P_ + p];
    in[c] = fmaxf(0.f, fmaf(x, sc[c], sh[c]));
  }
  float acc[8];
#pragma unroll
  for (int o = 0; o < 8; ++o){
    float a = bb[o];
#pragma unroll
    for (int c = 0; c < 8; ++c) a += in[c]*Wl[o*8+c];
    acc[o] = a;
  }
#pragma unroll
  for (int o = 0; o < 8; ++o) wb[(size_t)o*P_ + p] = acc[o];
}

// ---------------- WeightNet layer 2: bn relu 8->16 ------------------------
__global__ __launch_bounds__(256) void w2_kernel(const float* __restrict__ wb,
                                                 float* __restrict__ wb2,
                                                 const float* __restrict__ w,   // [16][8]
                                                 const float* __restrict__ bias,
                                                 const double* __restrict__ st,
                                                 const float* __restrict__ g,
                                                 const float* __restrict__ be){
  __shared__ float Wl[128], bb[16], sc[8], sh[8];
  if (threadIdx.x < 128) Wl[threadIdx.x] = w[threadIdx.x];
  if (threadIdx.x < 8)
    bn_coeff(st, g, be, threadIdx.x, (double)P_, &sc[threadIdx.x], &sh[threadIdx.x]);
  if (threadIdx.x < 16) bb[threadIdx.x] = bias[threadIdx.x];
  __syncthreads();
  const int p = blockIdx.x*256 + threadIdx.x;
  float in[8];
#pragma unroll
  for (int c = 0; c < 8; ++c){
    float x = wb[(size_t)c*P_ + p];
    in[c] = fmaxf(0.f, fmaf(x, sc[c], sh[c]));
  }
#pragma unroll
  for (int o = 0; o < 16; ++o){
    float a = bb[o];
#pragma unroll
    for (int c = 0; c < 8; ++c) a += in[c]*Wl[o*8+c];
    wb2[(size_t)o*P_ + p] = a;
  }
}

// ---------------- agg: per (b,s) [128,K]x[K,16] -> agg row [2048] ----------
__global__ __launch_bounds__(256) void agg_kernel(const float* __restrict__ y2,
                                                  const float* __restrict__ wb2,
                                                  const double* __restrict__ st2,
                                                  const float* __restrict__ g2,
                                                  const float* __restrict__ be2,
                                                  const double* __restrict__ stw,
                                                  const float* __restrict__ gw,
                                                  const float* __restrict__ bew,
                                                  float* __restrict__ agg){
  __shared__ float f[32*132];      // [k][c] padded
  __shared__ float wt[32*16];      // [k][w]
  __shared__ float sc2[128], sh2[128], scw[16], shw[16];
  const int t = threadIdx.x;
  if (t < 128) bn_coeff(st2, g2, be2, t, (double)P_, &sc2[t], &sh2[t]);
  if (t < 16)  bn_coeff(stw, gw, bew, t, (double)P_, &scw[t], &shw[t]);
  __syncthreads();
  const int bs = blockIdx.x;
  const size_t p0 = (size_t)bs * 32;
  for (int e = t; e < 4096; e += 256){
    int c = e >> 5, k = e & 31;
    float x = y2[(size_t)c*P_ + p0 + k];
    f[k*132 + c] = fmaxf(0.f, fmaf(x, sc2[c], sh2[c]));
  }
  for (int e = t; e < 512; e += 256){
    int w = e >> 5, k = e & 31;
    float x = wb2[(size_t)w*P_ + p0 + k];
    wt[k*16 + w] = fmaxf(0.f, fmaf(x, scw[w], shw[w]));
  }
  __syncthreads();
  const int c = t >> 1, wp = (t & 1) * 8;
  float a0=0,a1=0,a2=0,a3=0,a4=0,a5=0,a6=0,a7=0;
#pragma unroll
  for (int k = 0; k < 32; ++k){
    float fv = f[k*132 + c];
    float4 u = *reinterpret_cast<const float4*>(&wt[k*16 + wp]);
    float4 v = *reinterpret_cast<const float4*>(&wt[k*16 + wp + 4]);
    a0 += fv*u.x; a1 += fv*u.y; a2 += fv*u.z; a3 += fv*u.w;
    a4 += fv*v.x; a5 += fv*v.y; a6 += fv*v.z; a7 += fv*v.w;
  }
  float* dst = agg + (size_t)bs*2048 + c*16 + wp;
  *reinterpret_cast<float4*>(dst)     = make_float4(a0,a1,a2,a3);
  *reinterpret_cast<float4*>(dst + 4) = make_float4(a4,a5,a6,a7);
}

// ---------------- linear GEMM: [8192,2048] x [128,2048]^T + b --------------
__global__ __launch_bounds__(256) void lin_kernel(const float* __restrict__ agg,
                                                  const float* __restrict__ lw,
                                                  const float* __restrict__ lb,
                                                  float* __restrict__ outp){
  __shared__ float A[32*33];        // [r][kk] padded
  __shared__ float Wl[32*128];      // [kk][o]
  __shared__ float lbs[128];
  const int t = threadIdx.x;
  const int r0 = blockIdx.x * 32;
  if (t < 128) lbs[t] = lb[t];
  const int c_lane = t & 31, rg = t >> 5;   // cols c_lane+32j, rows rg*4+i
  float acc[4][4];
#pragma unroll
  for (int i = 0; i < 4; ++i)
#pragma unroll
    for (int j = 0; j < 4; ++j) acc[i][j] = 0.f;

  for (int kk0 = 0; kk0 < 2048; kk0 += 32){
    __syncthreads();
    { // stage A: 32x32
      int r = t >> 3, kq = (t & 7) * 4;
      float4 v = *reinterpret_cast<const float4*>(&agg[(size_t)(r0 + r)*2048 + kk0 + kq]);
      A[r*33 + kq]   = v.x; A[r*33 + kq+1] = v.y; A[r*33 + kq+2] = v.z; A[r*33 + kq+3] = v.w;
    }
    { // stage W: 128x32 transposed to [kk][o]
#pragma unroll
      for (int u = 0; u < 4; ++u){
        int fid = t + 256*u;
        int o = fid >> 3, kq = (fid & 7) * 4;
        float4 v = *reinterpret_cast<const float4*>(&lw[(size_t)o*2048 + kk0 + kq]);
        Wl[(kq  )*128 + o] = v.x; Wl[(kq+1)*128 + o] = v.y;
        Wl[(kq+2)*128 + o] = v.z; Wl[(kq+3)*128 + o] = v.w;
      }
    }
    __syncthreads();
#pragma unroll 8
    for (int kk = 0; kk < 32; ++kk){
      float a0 = A[(rg*4+0)*33 + kk], a1 = A[(rg*4+1)*33 + kk],
            a2 = A[(rg*4+2)*33 + kk], a3 = A[(rg*4+3)*33 + kk];
#pragma unroll
      for (int j = 0; j < 4; ++j){
        float wv = Wl[kk*128 + c_lane + 32*j];
        acc[0][j] += a0*wv; acc[1][j] += a1*wv; acc[2][j] += a2*wv; acc[3][j] += a3*wv;
      }
    }
  }
  __syncthreads();
#pragma unroll
  for (int i = 0; i < 4; ++i)
#pragma unroll
    for (int j = 0; j < 4; ++j){
      int o = c_lane + 32*j;
      outp[(size_t)(r0 + rg*4 + i)*128 + o] = acc[i][j] + lbs[o];
    }
}

// ---------------- final BN stats over (b,s) --------------------------------
__global__ __launch_bounds__(128) void statsF_kernel(const float* __restrict__ outp,
                                                     double* __restrict__ st){
  const int c = threadIdx.x;
  const int r0 = blockIdx.x * 128;
  double s = 0.0, q = 0.0;
  for (int r = 0; r < 128; ++r){
    double v = outp[(size_t)(r0 + r)*128 + c];
    s += v; q += v*v;
  }
  atomicAdd(&st[c*2], s); atomicAdd(&st[c*2+1], q);
}

// ---------------- final BN+relu + transpose to [B,128,S] -------------------
__global__ __launch_bounds__(256) void final_kernel(const float* __restrict__ outp,
                                                    const double* __restrict__ st,
                                                    const float* __restrict__ g,
                                                    const float* __restrict__ be,
                                                    float* __restrict__ out){
  const int gid = blockIdx.x*256 + threadIdx.x;     // b*131072 + o*1024 + s
  const int s = gid & 1023, o = (gid >> 10) & 127, b = gid >> 17;
  float sc, sh;
  bn_coeff(st, g, be, o, (double)BS_, &sc, &sh);
  float x = outp[((size_t)(b << 10) + s)*128 + o];
  out[gid] = fmaxf(0.f, fmaf(x, sc, sh));
}

// ---------------------------------------------------------------------------
extern "C" void kernel_launch(void* const* d_in, const int* in_sizes, int n_in,
                              void* d_out, int out_size, void* d_ws, size_t ws_size,
                              hipStream_t stream){
  (void)in_sizes; (void)n_in; (void)out_size; (void)ws_size;
  const float* xyz    = (const float*)d_in[0];
  const float* points = (const float*)d_in[1];
  const float* mw0 = (const float*)d_in[2],  *mb0 = (const float*)d_in[3],
             * mg0 = (const float*)d_in[4],  *me0 = (const float*)d_in[5];
  const float* mw1 = (const float*)d_in[6],  *mb1 = (const float*)d_in[7],
             * mg1 = (const float*)d_in[8],  *me1 = (const float*)d_in[9];
  const float* mw2 = (const float*)d_in[10], *mb2 = (const float*)d_in[11],
             * mg2 = (const float*)d_in[12], *me2 = (const float*)d_in[13];
  const float* ww0 = (const float*)d_in[14], *wb0 = (const float*)d_in[15],
             * wg0 = (const float*)d_in[16], *we0 = (const float*)d_in[17];
  const float* ww1 = (const float*)d_in[18], *wb1 = (const float*)d_in[19],
             * wg1 = (const float*)d_in[20], *we1 = (const float*)d_in[21];
  const float* ww2 = (const float*)d_in[22], *wb2_ = (const float*)d_in[23],
             * wg2 = (const float*)d_in[24], *we2 = (const float*)d_in[25];
  const float* lw  = (const float*)d_in[26], *lb  = (const float*)d_in[27];
  const float* fg  = (const float*)d_in[28], *fb  = (const float*)d_in[29];

  char* ws = (char*)d_ws;
  double* ST0 = (double*)(ws + OFF_STATS);
  double* ST1 = (double*)(ws + OFF_STATS + 1024);
  double* ST2 = (double*)(ws + OFF_STATS + 2048);
  double* SW0 = (double*)(ws + OFF_STATS + 4096);
  double* SW1 = (double*)(ws + OFF_STATS + 4224);
  double* SW2 = (double*)(ws + OFF_STATS + 4352);
  double* STF = (double*)(ws + OFF_STATS + 4608);
  int*   fpsidx = (int*)(ws + OFF_FPSIDX);
  float* nxyz   = (float*)(ws + OFF_NEWXYZ);
  int*   knnidx = (int*)(ws + OFF_KNN);
  float* pT     = (float*)(ws + OFF_PT);
  float* y01    = (float*)(ws + OFF_Y01);
  float* y2     = (float*)(ws + OFF_Y2);
  float* w01    = (float*)(ws + OFF_W01);
  float* w2b    = (float*)(ws + OFF_W2B);
  float* aggbuf = (float*)(ws + OFF_Y01);   // alias: y01 dead after m2
  float* outpre = (float*)(ws + OFF_OUTPRE);

  float* out_xyz  = (float*)d_out;                      // [B,3,S]
  float* out_feat = (float*)d_out + (size_t)B_*3*S_;    // [B,128,S]

  hipMemsetAsync(ws + OFF_STATS, 0, 8192, stream);

  tr_kernel<<<dim3(B_*64), dim3(64), 0, stream>>>(points, pT);

  StartIdx st = compute_starts();
  fps_kernel<<<dim3(B_), dim3(256), 0, stream>>>(xyz, st, fpsidx, nxyz, out_xyz);

  knn_kernel<<<dim3(BS_/4), dim3(256), 0, stream>>>(xyz, nxyz, knnidx);

  m0_kernel<<<dim3(P_/256), dim3(256), 0, stream>>>(pT, xyz, nxyz, knnidx, mw0, mb0, y01);
  stats_kernel<<<dim3(64*8), dim3(256), 0, stream>>>(y01, ST0, 64);
  m1_kernel<<<dim3(P_/256), dim3(256), 0, stream>>>(y01, mw1, mb1, ST0, mg0, me0);
  stats_kernel<<<dim3(64*8), dim3(256), 0, stream>>>(y01, ST1, 64);
  m2_kernel<<<dim3(P_/256, 2), dim3(256), 0, stream>>>(y01, y2, mw2, mb2, ST1, mg1, me1);
  stats_kernel<<<dim3(128*8), dim3(256), 0, stream>>>(y2, ST2, 128);

  w0_kernel<<<dim3(P_/256), dim3(256), 0, stream>>>(xyz, nxyz, knnidx, ww0, wb0, w01);
  stats_kernel<<<dim3(8*8), dim3(256), 0, stream>>>(w01, SW0, 8);
  w1_kernel<<<dim3(P_/256), dim3(256), 0, stream>>>(w01, ww1, wb1, SW0, wg0, we0);
  stats_kernel<<<dim3(8*8), dim3(256), 0, stream>>>(w01, SW1, 8);
  w2_kernel<<<dim3(P_/256), dim3(256), 0, stream>>>(w01, w2b, ww2, wb2_, SW1, wg1, we1);
  stats_kernel<<<dim3(16*8), dim3(256), 0, stream>>>(w2b, SW2, 16);

  agg_kernel<<<dim3(BS_), dim3(256), 0, stream>>>(y2, w2b, ST2, mg2, me2, SW2, wg2, we2, aggbuf);
  lin_kernel<<<dim3(BS_/32), dim3(256), 0, stream>>>(aggbuf, lw, lb, outpre);
  statsF_kernel<<<dim3(BS_/128), dim3(128), 0, stream>>>(outpre, STF);
  final_kernel<<<dim3((B_*128*S_)/256), dim3(256), 0, stream>>>(outpre, STF, fg, fb, out_feat);
}